// Round 1
// baseline (37908.463 us; speedup 1.0000x reference)
//
#include <hip/hip_runtime.h>
#include <hip/hip_bf16.h>

// ---------------------------------------------------------------------------
// SA_NET: LSTM(4096 steps, H=512) scan  +  CNN branch on first 512 rows  +
//         MLP head -> single sigmoid scalar.
// Strategy: persistent-grid LSTM with register-resident weights and
// flag-based cross-block sync (latency-bound recurrence); CNN via
// im2col + generic tiled fp32 GEMM; everything fp32.
// ---------------------------------------------------------------------------

#define HSZ   512
#define ESZ   300
#define NBLK  64      // LSTM blocks; 64 flags == one wave of lanes

__device__ __forceinline__ float sigf(float x) {
    return 1.f / (1.f + __expf(-x));
}
__device__ __forceinline__ float tanh_fast(float x) {
    // 1 - 2/(e^{2x}+1); saturates correctly at +-inf, ~1e-6 rel err
    return 1.f - 2.f / (__expf(2.f * x) + 1.f);
}

// ---------------------------------------------------------------------------
// Persistent LSTM. 64 blocks x 256 threads. Block b owns h[8b..8b+7].
// Thread map: dot = tid>>3 (0..31) -> (jl = dot>>2, gate = dot&3); seg = tid&7
// covers h[seg*64 .. seg*64+63] of the dot product. One wave = 2 j's.
// ---------------------------------------------------------------------------
__global__ __launch_bounds__(256, 1) void lstm_kernel(
    const float* __restrict__ inputs, const float* __restrict__ w_ih,
    const float* __restrict__ w_hh, const float* __restrict__ b_ih,
    const float* __restrict__ b_hh,
    float* hbuf /*2*512*/, int* flags /*64*/, float* hmean /*512*/, int T)
{
    const int tid  = threadIdx.x;
    const int lane = tid & 63;
    const int wave = tid >> 6;
    const int dot  = tid >> 3;          // 0..31
    const int seg  = tid & 7;
    const int gate = dot & 3;
    const int jl   = dot >> 2;          // 0..7
    const int j    = blockIdx.x * 8 + jl;
    const int row  = gate * HSZ + j;    // row in w_hh / gate vector

    // --- register-resident weights ---
    float4 wh[16];
    {
        const float4* whp = (const float4*)(w_hh + (size_t)row * HSZ + seg * 64);
#pragma unroll
        for (int i = 0; i < 16; ++i) wh[i] = whp[i];
    }
    // x-part: seg<7 covers e=[40*seg,40*seg+40); seg==7 covers e=[260,300)
    // with first 20 weights zeroed (overlap with seg 6). All loads in-bounds.
    const int base = (seg == 7) ? 260 : seg * 40;
    float wx[40];
    {
        const float* wxp = w_ih + (size_t)row * ESZ + base;
#pragma unroll
        for (int i = 0; i < 40; ++i) {
            bool valid = (seg < 7) || (i >= 20);
            wx[i] = valid ? wxp[i] : 0.f;
        }
    }
    const float bias = b_ih[row] + b_hh[row];

    float c = 0.f, hsum = 0.f;
    const int l0 = lane & 32;           // base lane of my half-wave (one j)

    for (int s = 1; s <= T; ++s) {
        const int t    = s - 1;
        const int cur  = s & 1;
        const int prev = cur ^ 1;

        // ---- x_t part: independent of h, computed BEFORE the poll ----
        float acc = 0.f;
        {
            const float4* xp4 = (const float4*)(inputs + (size_t)t * ESZ + base);
#pragma unroll
            for (int i4 = 0; i4 < 10; ++i4) {
                float4 x4 = xp4[i4];
                acc += wx[i4 * 4 + 0] * x4.x + wx[i4 * 4 + 1] * x4.y +
                       wx[i4 * 4 + 2] * x4.z + wx[i4 * 4 + 3] * x4.w;
            }
        }

        // ---- wait for h_{s-1} (all 64 block flags >= s-1) ----
        if (s > 1) {
            const int target = s - 1;
            while (true) {
                int f = __hip_atomic_load(&flags[lane], __ATOMIC_RELAXED,
                                          __HIP_MEMORY_SCOPE_AGENT);
                if (__all(f >= target)) break;
            }
            __threadfence();   // agent acquire: invalidate stale cached h
        }

        // ---- h part ----
        {
            const float4* hp = (const float4*)(hbuf + prev * HSZ + seg * 64);
#pragma unroll
            for (int i = 0; i < 16; ++i) {
                float4 h4 = hp[i];
                acc += wh[i].x * h4.x + wh[i].y * h4.y +
                       wh[i].z * h4.z + wh[i].w * h4.w;
            }
        }
        // reduce across the 8 seg lanes (stays inside the 8-lane group)
        acc += __shfl_xor(acc, 4, 64);
        acc += __shfl_xor(acc, 2, 64);
        acc += __shfl_xor(acc, 1, 64);
        float pre = acc + bias;

        // gather the 4 gates of my half-wave's j
        float gi = __shfl(pre, l0 + 0,  64);
        float gf = __shfl(pre, l0 + 8,  64);
        float gg = __shfl(pre, l0 + 16, 64);
        float go = __shfl(pre, l0 + 24, 64);

        float is = sigf(gi), fs = sigf(gf), os = sigf(go);
        float gt = tanh_fast(gg);
        c = fs * c + is * gt;
        float h = os * tanh_fast(c);

        if ((lane & 31) == 0) {
            hsum += h;
            int j2 = blockIdx.x * 8 + wave * 2 + (lane >> 5);
            hbuf[cur * HSZ + j2] = h;
        }
        __syncthreads();                 // drains vmem -> h stores in L2
        if (tid == 0)
            __hip_atomic_store(&flags[blockIdx.x], s, __ATOMIC_RELEASE,
                               __HIP_MEMORY_SCOPE_AGENT);
    }

    if ((lane & 31) == 0) {
        int j2 = blockIdx.x * 8 + wave * 2 + (lane >> 5);
        hmean[j2] = hsum * (1.f / (float)T);
    }
}

// ---------------------------------------------------------------------------
// Generic tiled fp32 GEMM: C[M,N] = A[M,K] * B[N,K]^T + bias[n]
// 32x32 tile, 256 threads, 2x2 per thread. Guards on all edges.
// ---------------------------------------------------------------------------
__global__ __launch_bounds__(256) void gemm32(
    const float* __restrict__ A, const float* __restrict__ B,
    const float* __restrict__ bias, float* __restrict__ C,
    int M, int N, int K)
{
    __shared__ float As[32][33];
    __shared__ float Bs[32][33];
    const int tid = threadIdx.x;
    const int m0 = blockIdx.y * 32, n0 = blockIdx.x * 32;
    const int tn = (tid & 15) * 2, tm = (tid >> 4) * 2;
    float a00 = 0, a01 = 0, a10 = 0, a11 = 0;

    for (int kk = 0; kk < K; kk += 32) {
        const int k = tid & 31, r = tid >> 5;
#pragma unroll
        for (int jj = 0; jj < 4; ++jj) {
            int m = r + jj * 8;
            As[k][m] = (kk + k < K && m0 + m < M)
                         ? A[(size_t)(m0 + m) * K + kk + k] : 0.f;
            Bs[k][m] = (kk + k < K && n0 + m < N)
                         ? B[(size_t)(n0 + m) * K + kk + k] : 0.f;
        }
        __syncthreads();
#pragma unroll
        for (int k2 = 0; k2 < 32; ++k2) {
            float x0 = As[k2][tm], x1 = As[k2][tm + 1];
            float y0 = Bs[k2][tn], y1 = Bs[k2][tn + 1];
            a00 += x0 * y0; a01 += x0 * y1;
            a10 += x1 * y0; a11 += x1 * y1;
        }
        __syncthreads();
    }
    const int m = m0 + tm, n = n0 + tn;
    if (m < M) {
        if (n     < N) C[(size_t)m * N + n]     = a00 + bias[n];
        if (n + 1 < N) C[(size_t)m * N + n + 1] = a01 + bias[n + 1];
    }
    if (m + 1 < M) {
        if (n     < N) C[(size_t)(m + 1) * N + n]     = a10 + bias[n];
        if (n + 1 < N) C[(size_t)(m + 1) * N + n + 1] = a11 + bias[n + 1];
    }
}

// im2col for conv1: X[t*2100 + dt*300 + e] = in[(t+dt-3)*300+e] (zero pad)
__global__ void im2col1(const float* __restrict__ in, float* __restrict__ X)
{
    int idx = blockIdx.x * 256 + threadIdx.x;
    if (idx >= 512 * 2100) return;
    int t = idx / 2100, k = idx - t * 2100;
    int dt = k / 300, e = k - dt * 300;
    int tt = t + dt - 3;
    X[idx] = (tt >= 0 && tt < 512) ? in[tt * 300 + e] : 0.f;
}

// generic 1d im2col: X[t*(Cin*KW) + c*KW + dk] = S[c*L + t+dk-pad] (zero pad)
__global__ void im2colN(const float* __restrict__ S, float* __restrict__ X,
                        int L, int Cin, int KW, int pad, int total)
{
    int idx = blockIdx.x * 256 + threadIdx.x;
    if (idx >= total) return;
    int KC = Cin * KW;
    int t = idx / KC, r = idx - t * KC;
    int c = r / KW, dk = r - c * KW;
    int tt = t + dk - pad;
    X[idx] = (tt >= 0 && tt < L) ? S[c * L + tt] : 0.f;
}

// X4[t*256+c] = s3[c*64+t]
__global__ void transpose4(const float* __restrict__ S, float* __restrict__ X)
{
    int idx = blockIdx.x * 256 + threadIdx.x;
    if (idx >= 64 * 256) return;
    int t = idx >> 8, c = idx & 255;
    X[idx] = S[c * 64 + t];
}

// S[c*LP+tp] = sig(max(C[(2tp)*Cch+c], C[(2tp+1)*Cch+c]))
__global__ void poolsig(const float* __restrict__ Cin_, float* __restrict__ S,
                        int Cch, int LP)
{
    int idx = blockIdx.x * 256 + threadIdx.x;
    if (idx >= Cch * LP) return;
    int c = idx / LP, tp = idx - c * LP;
    float a = Cin_[(2 * tp) * Cch + c];
    float b = Cin_[(2 * tp + 1) * Cch + c];
    S[idx] = sigf(fmaxf(a, b));
}

// y[o*64+t] = sig(C4[t*16+o])
__global__ void sigy(const float* __restrict__ C4, float* __restrict__ y)
{
    int idx = blockIdx.x * 256 + threadIdx.x;
    if (idx >= 1024) return;
    int o = idx >> 6, t = idx & 63;
    y[idx] = sigf(C4[t * 16 + o]);
}

// fc1: 128 blocks x 64 lanes; x = [hmean(512) | y(1024)]
__global__ void fc1_kernel(const float* __restrict__ hmean,
                           const float* __restrict__ y,
                           const float* __restrict__ w,
                           const float* __restrict__ b,
                           float* __restrict__ out)
{
    int k = blockIdx.x, lane = threadIdx.x;
    float a = 0.f;
    for (int i = lane; i < 1536; i += 64) {
        float xv = (i < 512) ? hmean[i] : y[i - 512];
        a += xv * w[k * 1536 + i];
    }
#pragma unroll
    for (int off = 32; off; off >>= 1) a += __shfl_xor(a, off, 64);
    if (lane == 0) out[k] = sigf(a + b[k]);
}

// fc2 (32x128) + fc3 (1x32), single block
__global__ void head_kernel(const float* __restrict__ x2,
                            const float* __restrict__ w2, const float* __restrict__ b2,
                            const float* __restrict__ w3, const float* __restrict__ b3,
                            float* __restrict__ out)
{
    __shared__ float x3[32];
    int lane = threadIdx.x;
    if (lane < 32) {
        float a = 0.f;
        for (int i = 0; i < 128; ++i) a += x2[i] * w2[lane * 128 + i];
        x3[lane] = sigf(a + b2[lane]);
    }
    __syncthreads();
    if (lane == 0) {
        float a = 0.f;
        for (int i = 0; i < 32; ++i) a += x3[i] * w3[i];
        out[0] = sigf(a + b3[0]);
    }
}

extern "C" void kernel_launch(void* const* d_in, const int* in_sizes, int n_in,
                              void* d_out, int out_size, void* d_ws, size_t ws_size,
                              hipStream_t stream)
{
    const float* inputs = (const float*)d_in[0];
    const float* w_ih   = (const float*)d_in[1];
    const float* w_hh   = (const float*)d_in[2];
    const float* b_ih   = (const float*)d_in[3];
    const float* b_hh   = (const float*)d_in[4];
    const float* c1w    = (const float*)d_in[5];
    const float* c1b    = (const float*)d_in[6];
    const float* c2w    = (const float*)d_in[7];
    const float* c2b    = (const float*)d_in[8];
    const float* c3w    = (const float*)d_in[9];
    const float* c3b    = (const float*)d_in[10];
    const float* c4w    = (const float*)d_in[11];
    const float* c4b    = (const float*)d_in[12];
    const float* fc1w   = (const float*)d_in[13];
    const float* fc1b   = (const float*)d_in[14];
    const float* fc2w   = (const float*)d_in[15];
    const float* fc2b   = (const float*)d_in[16];
    const float* fc3w   = (const float*)d_in[17];
    const float* fc3b   = (const float*)d_in[18];
    float* out = (float*)d_out;
    const int T = in_sizes[0] / ESZ;   // 4096

    // ---- workspace layout (floats) ----
    float* p     = (float*)d_ws;
    float* hbuf  = p;                         // 1024 (2 x 512 ping-pong)
    int*   flags = (int*)(p + 1024);          // 64
    float* hmean = p + 1088;                  // 512
    float* X1 = p + 1600;                     // 512*2100 = 1075200
    float* C1 = X1 + 1075200;                 // 512*256  = 131072
    float* s1 = C1 + 131072;                  // 256*256  = 65536
    float* X2 = s1 + 65536;                   // 256*1280 = 327680
    float* C2 = X2 + 327680;                  // 256*64   = 16384
    float* s2 = C2 + 16384;                   // 64*128   = 8192
    float* X3 = s2 + 8192;                    // 128*192  = 24576
    float* C3 = X3 + 24576;                   // 128*256  = 32768
    float* s3 = C3 + 32768;                   // 256*64   = 16384
    float* X4 = s3 + 16384;                   // 64*256   = 16384
    float* C4 = X4 + 16384;                   // 64*16    = 1024
    float* yb = C4 + 1024;                    // 1024
    float* x2 = yb + 1024;                    // 128

    // zero h0 ping-pong buffers + flags (re-run safe across graph replays)
    hipMemsetAsync(p, 0, 1088 * sizeof(float), stream);

    // ---- LSTM (dominant) ----
    lstm_kernel<<<NBLK, 256, 0, stream>>>(inputs, w_ih, w_hh, b_ih, b_hh,
                                          hbuf, flags, hmean, T);

    // ---- CNN branch ----
    im2col1<<<4200, 256, 0, stream>>>(inputs, X1);
    gemm32<<<dim3(8, 16), 256, 0, stream>>>(X1, c1w, c1b, C1, 512, 256, 2100);
    poolsig<<<256, 256, 0, stream>>>(C1, s1, 256, 256);

    im2colN<<<1280, 256, 0, stream>>>(s1, X2, 256, 256, 5, 2, 256 * 1280);
    gemm32<<<dim3(2, 8), 256, 0, stream>>>(X2, c2w, c2b, C2, 256, 64, 1280);
    poolsig<<<32, 256, 0, stream>>>(C2, s2, 64, 128);

    im2colN<<<96, 256, 0, stream>>>(s2, X3, 128, 64, 3, 1, 128 * 192);
    gemm32<<<dim3(8, 4), 256, 0, stream>>>(X3, c3w, c3b, C3, 128, 256, 192);
    poolsig<<<64, 256, 0, stream>>>(C3, s3, 256, 64);

    transpose4<<<64, 256, 0, stream>>>(s3, X4);
    gemm32<<<dim3(1, 2), 256, 0, stream>>>(X4, c4w, c4b, C4, 64, 16, 256);
    sigy<<<4, 256, 0, stream>>>(C4, yb);

    // ---- MLP head ----
    fc1_kernel<<<128, 64, 0, stream>>>(hmean, yb, fc1w, fc1b, x2);
    head_kernel<<<1, 64, 0, stream>>>(x2, fc2w, fc2b, fc3w, fc3b, out);
}

// Round 2
// 10500.630 us; speedup vs baseline: 3.6101x; 3.6101x over previous
//
#include <hip/hip_runtime.h>
#include <hip/hip_bf16.h>

// ---------------------------------------------------------------------------
// SA_NET: LSTM(4096 steps, H=512) + CNN branch + MLP head.
// Round 1: fence-free LSTM sync via packed (tag,value) 8B relaxed agent
// atomics (no threadfence / no L2 writeback per step), and x-part hoisted
// out of the recurrence into a precomputed GEMM G = x W_ih^T + biases.
// ---------------------------------------------------------------------------

#define HSZ   512
#define ESZ   300
#define NBLK  64      // LSTM blocks: block b owns h[8b..8b+7]

__device__ __forceinline__ float sigf(float x) {
    return 1.f / (1.f + __expf(-x));
}
__device__ __forceinline__ float tanh_fast(float x) {
    return 1.f - 2.f / (__expf(2.f * x) + 1.f);
}

// ---------------------------------------------------------------------------
// Persistent LSTM. 64 blocks x 256 threads. Thread map: dot = tid>>3 (0..31)
// -> (jl = dot>>2, gate = dot&3); seg = tid&7 covers 64 h-elems of the dot.
// h exchanged via hpack[2][512]: 8-byte words = (step<<32)|f32bits, relaxed
// AGENT atomics (coherent at LLC) -> no fences anywhere.
// ---------------------------------------------------------------------------
template<bool USE_G>
__global__ __launch_bounds__(256, 1) void lstm_kernel(
    const float* __restrict__ inputs, const float* __restrict__ w_ih,
    const float* __restrict__ w_hh, const float* __restrict__ b_ih,
    const float* __restrict__ b_hh, const float* __restrict__ G,
    unsigned long long* hpack /*2*512*/, float* hmean /*512*/, int T)
{
    __shared__ float hlds[2][512];
    const int tid  = threadIdx.x;
    const int lane = tid & 63;
    const int wave = tid >> 6;
    const int dot  = tid >> 3;          // 0..31
    const int seg  = tid & 7;
    const int gate = dot & 3;
    const int jl   = dot >> 2;          // 0..7
    const int j    = blockIdx.x * 8 + jl;
    const int row  = gate * HSZ + j;    // row in w_hh / gate vector

    // --- register-resident recurrent weights: 64 floats/thread ---
    float4 wh[16];
    {
        const float4* whp = (const float4*)(w_hh + (size_t)row * HSZ + seg * 64);
#pragma unroll
        for (int i = 0; i < 16; ++i) wh[i] = whp[i];
    }

    // fallback-only: register x-weights (seg 7 covers e=[260,300), first 20 zeroed)
    int base = 0;
    float wx[40];
    float bias = 0.f;
    if (!USE_G) {
        base = (seg == 7) ? 260 : seg * 40;
        const float* wxp = w_ih + (size_t)row * ESZ + base;
#pragma unroll
        for (int i = 0; i < 40; ++i) {
            bool valid = (seg < 7) || (i >= 20);
            wx[i] = valid ? wxp[i] : 0.f;
        }
        bias = b_ih[row] + b_hh[row];
    }

    float c = 0.f, hsum = 0.f;
    const int l0 = lane & 32;           // base lane of my half-wave (one j)
    const int j2 = blockIdx.x * 8 + wave * 2 + (lane >> 5);  // writer's h index

    for (int s = 1; s <= T; ++s) {
        const int t = s - 1;

        // ---- pre-activation x-part (independent of h; issued before poll) ----
        float acc;
        if (USE_G) {
            acc = (seg == 0) ? G[(size_t)t * (4 * HSZ) + row] : 0.f;
        } else {
            acc = (seg == 0) ? bias : 0.f;
            const float4* xp4 = (const float4*)(inputs + (size_t)t * ESZ + base);
#pragma unroll
            for (int i4 = 0; i4 < 10; ++i4) {
                float4 x4 = xp4[i4];
                acc += wx[i4 * 4 + 0] * x4.x + wx[i4 * 4 + 1] * x4.y +
                       wx[i4 * 4 + 2] * x4.z + wx[i4 * 4 + 3] * x4.w;
            }
        }

        // ---- poll h_{s-1}: slot t&1, tag t; each thread owns 2 words ----
        {
            unsigned long long* slot = hpack + (size_t)(t & 1) * HSZ;
            unsigned long long v0 = 0, v1 = 0;
            bool r0 = false, r1 = false;
            do {
                if (!r0) {
                    v0 = __hip_atomic_load(slot + tid, __ATOMIC_RELAXED,
                                           __HIP_MEMORY_SCOPE_AGENT);
                    r0 = (unsigned)(v0 >> 32) == (unsigned)t;
                }
                if (!r1) {
                    v1 = __hip_atomic_load(slot + tid + 256, __ATOMIC_RELAXED,
                                           __HIP_MEMORY_SCOPE_AGENT);
                    r1 = (unsigned)(v1 >> 32) == (unsigned)t;
                }
            } while (!(r0 && r1));
            union { unsigned u; float f; } c0, c1;
            c0.u = (unsigned)v0; c1.u = (unsigned)v1;
            hlds[t & 1][tid]       = c0.f;
            hlds[t & 1][tid + 256] = c1.f;
        }
        __syncthreads();   // single barrier per step (hlds is parity-buffered)

        // ---- h-matvec from LDS ----
        {
            const float4* hp = (const float4*)(&hlds[t & 1][seg * 64]);
#pragma unroll
            for (int i = 0; i < 16; ++i) {
                float4 h4 = hp[i];
                acc += wh[i].x * h4.x + wh[i].y * h4.y +
                       wh[i].z * h4.z + wh[i].w * h4.w;
            }
        }
        // reduce across the 8 seg lanes
        acc += __shfl_xor(acc, 4, 64);
        acc += __shfl_xor(acc, 2, 64);
        acc += __shfl_xor(acc, 1, 64);

        // gather the 4 gates of my half-wave's j
        float gi = __shfl(acc, l0 + 0,  64);
        float gf = __shfl(acc, l0 + 8,  64);
        float gg = __shfl(acc, l0 + 16, 64);
        float go = __shfl(acc, l0 + 24, 64);

        float is = sigf(gi), fs = sigf(gf), os = sigf(go);
        float gt = tanh_fast(gg);
        c = fs * c + is * gt;
        float h = os * tanh_fast(c);

        if ((lane & 31) == 0) {
            hsum += h;
            union { float f; unsigned u; } hv; hv.f = h;
            unsigned long long pk =
                ((unsigned long long)(unsigned)s << 32) | (unsigned long long)hv.u;
            __hip_atomic_store(&hpack[(size_t)(s & 1) * HSZ + j2], pk,
                               __ATOMIC_RELAXED, __HIP_MEMORY_SCOPE_AGENT);
        }
    }

    if ((lane & 31) == 0)
        hmean[j2] = hsum * (1.f / (float)T);
}

// ---------------------------------------------------------------------------
// G = inputs[M,K] * w_ih[N,K]^T + (b_ih+b_hh)  — 64x64 tile, 4x4/thread
// ---------------------------------------------------------------------------
__global__ __launch_bounds__(256) void gemm_g(
    const float* __restrict__ A, const float* __restrict__ B,
    const float* __restrict__ bi, const float* __restrict__ bh,
    float* __restrict__ C, int M, int N, int K)
{
    __shared__ float As[16][65];
    __shared__ float Bs[16][65];
    const int tid = threadIdx.x;
    const int m0 = blockIdx.y * 64, n0 = blockIdx.x * 64;
    const int tm = (tid >> 4) * 4, tn = (tid & 15) * 4;
    const int lr = tid >> 2;          // 0..63 tile row
    const int lk = (tid & 3) * 4;     // 0,4,8,12
    float acc[4][4] = {};

    for (int kk = 0; kk < K; kk += 16) {
#pragma unroll
        for (int i = 0; i < 4; ++i) {
            int k = lk + i;
            As[k][lr] = (kk + k < K && m0 + lr < M)
                          ? A[(size_t)(m0 + lr) * K + kk + k] : 0.f;
            Bs[k][lr] = (kk + k < K)
                          ? B[(size_t)(n0 + lr) * K + kk + k] : 0.f;
        }
        __syncthreads();
#pragma unroll
        for (int k2 = 0; k2 < 16; ++k2) {
            float a0 = As[k2][tm], a1 = As[k2][tm + 1],
                  a2 = As[k2][tm + 2], a3 = As[k2][tm + 3];
            float b0 = Bs[k2][tn], b1 = Bs[k2][tn + 1],
                  b2 = Bs[k2][tn + 2], b3 = Bs[k2][tn + 3];
            acc[0][0] += a0 * b0; acc[0][1] += a0 * b1;
            acc[0][2] += a0 * b2; acc[0][3] += a0 * b3;
            acc[1][0] += a1 * b0; acc[1][1] += a1 * b1;
            acc[1][2] += a1 * b2; acc[1][3] += a1 * b3;
            acc[2][0] += a2 * b0; acc[2][1] += a2 * b1;
            acc[2][2] += a2 * b2; acc[2][3] += a2 * b3;
            acc[3][0] += a3 * b0; acc[3][1] += a3 * b1;
            acc[3][2] += a3 * b2; acc[3][3] += a3 * b3;
        }
        __syncthreads();
    }
#pragma unroll
    for (int i = 0; i < 4; ++i) {
        int m = m0 + tm + i;
        if (m >= M) break;
#pragma unroll
        for (int jj = 0; jj < 4; ++jj) {
            int n = n0 + tn + jj;
            C[(size_t)m * N + n] = acc[i][jj] + bi[n] + bh[n];
        }
    }
}

// ---------------------------------------------------------------------------
// Generic tiled fp32 GEMM for CNN: C[M,N] = A[M,K]*B[N,K]^T + bias[n]
// ---------------------------------------------------------------------------
__global__ __launch_bounds__(256) void gemm32(
    const float* __restrict__ A, const float* __restrict__ B,
    const float* __restrict__ bias, float* __restrict__ C,
    int M, int N, int K)
{
    __shared__ float As[32][33];
    __shared__ float Bs[32][33];
    const int tid = threadIdx.x;
    const int m0 = blockIdx.y * 32, n0 = blockIdx.x * 32;
    const int tn = (tid & 15) * 2, tm = (tid >> 4) * 2;
    float a00 = 0, a01 = 0, a10 = 0, a11 = 0;

    for (int kk = 0; kk < K; kk += 32) {
        const int k = tid & 31, r = tid >> 5;
#pragma unroll
        for (int jj = 0; jj < 4; ++jj) {
            int m = r + jj * 8;
            As[k][m] = (kk + k < K && m0 + m < M)
                         ? A[(size_t)(m0 + m) * K + kk + k] : 0.f;
            Bs[k][m] = (kk + k < K && n0 + m < N)
                         ? B[(size_t)(n0 + m) * K + kk + k] : 0.f;
        }
        __syncthreads();
#pragma unroll
        for (int k2 = 0; k2 < 32; ++k2) {
            float x0 = As[k2][tm], x1 = As[k2][tm + 1];
            float y0 = Bs[k2][tn], y1 = Bs[k2][tn + 1];
            a00 += x0 * y0; a01 += x0 * y1;
            a10 += x1 * y0; a11 += x1 * y1;
        }
        __syncthreads();
    }
    const int m = m0 + tm, n = n0 + tn;
    if (m < M) {
        if (n     < N) C[(size_t)m * N + n]     = a00 + bias[n];
        if (n + 1 < N) C[(size_t)m * N + n + 1] = a01 + bias[n + 1];
    }
    if (m + 1 < M) {
        if (n     < N) C[(size_t)(m + 1) * N + n]     = a10 + bias[n];
        if (n + 1 < N) C[(size_t)(m + 1) * N + n + 1] = a11 + bias[n + 1];
    }
}

// im2col for conv1: X[t*2100 + dt*300 + e] = in[(t+dt-3)*300+e] (zero pad)
__global__ void im2col1(const float* __restrict__ in, float* __restrict__ X)
{
    int idx = blockIdx.x * 256 + threadIdx.x;
    if (idx >= 512 * 2100) return;
    int t = idx / 2100, k = idx - t * 2100;
    int dt = k / 300, e = k - dt * 300;
    int tt = t + dt - 3;
    X[idx] = (tt >= 0 && tt < 512) ? in[tt * 300 + e] : 0.f;
}

// generic 1d im2col: X[t*(Cin*KW) + c*KW + dk] = S[c*L + t+dk-pad] (zero pad)
__global__ void im2colN(const float* __restrict__ S, float* __restrict__ X,
                        int L, int Cin, int KW, int pad, int total)
{
    int idx = blockIdx.x * 256 + threadIdx.x;
    if (idx >= total) return;
    int KC = Cin * KW;
    int t = idx / KC, r = idx - t * KC;
    int c = r / KW, dk = r - c * KW;
    int tt = t + dk - pad;
    X[idx] = (tt >= 0 && tt < L) ? S[c * L + tt] : 0.f;
}

// X4[t*256+c] = s3[c*64+t]
__global__ void transpose4(const float* __restrict__ S, float* __restrict__ X)
{
    int idx = blockIdx.x * 256 + threadIdx.x;
    if (idx >= 64 * 256) return;
    int t = idx >> 8, c = idx & 255;
    X[idx] = S[c * 64 + t];
}

// S[c*LP+tp] = sig(max(C[(2tp)*Cch+c], C[(2tp+1)*Cch+c]))
__global__ void poolsig(const float* __restrict__ Cin_, float* __restrict__ S,
                        int Cch, int LP)
{
    int idx = blockIdx.x * 256 + threadIdx.x;
    if (idx >= Cch * LP) return;
    int c = idx / LP, tp = idx - c * LP;
    float a = Cin_[(2 * tp) * Cch + c];
    float b = Cin_[(2 * tp + 1) * Cch + c];
    S[idx] = sigf(fmaxf(a, b));
}

// y[o*64+t] = sig(C4[t*16+o])
__global__ void sigy(const float* __restrict__ C4, float* __restrict__ y)
{
    int idx = blockIdx.x * 256 + threadIdx.x;
    if (idx >= 1024) return;
    int o = idx >> 6, t = idx & 63;
    y[idx] = sigf(C4[t * 64 ? t * 16 + o : t * 16 + o]);
}

// fc1: 128 blocks x 64 lanes; x = [hmean(512) | y(1024)]
__global__ void fc1_kernel(const float* __restrict__ hmean,
                           const float* __restrict__ y,
                           const float* __restrict__ w,
                           const float* __restrict__ b,
                           float* __restrict__ out)
{
    int k = blockIdx.x, lane = threadIdx.x;
    float a = 0.f;
    for (int i = lane; i < 1536; i += 64) {
        float xv = (i < 512) ? hmean[i] : y[i - 512];
        a += xv * w[k * 1536 + i];
    }
#pragma unroll
    for (int off = 32; off; off >>= 1) a += __shfl_xor(a, off, 64);
    if (lane == 0) out[k] = sigf(a + b[k]);
}

// fc2 (32x128) + fc3 (1x32), single block
__global__ void head_kernel(const float* __restrict__ x2,
                            const float* __restrict__ w2, const float* __restrict__ b2,
                            const float* __restrict__ w3, const float* __restrict__ b3,
                            float* __restrict__ out)
{
    __shared__ float x3[32];
    int lane = threadIdx.x;
    if (lane < 32) {
        float a = 0.f;
        for (int i = 0; i < 128; ++i) a += x2[i] * w2[lane * 128 + i];
        x3[lane] = sigf(a + b2[lane]);
    }
    __syncthreads();
    if (lane == 0) {
        float a = 0.f;
        for (int i = 0; i < 32; ++i) a += x3[i] * w3[i];
        out[0] = sigf(a + b3[0]);
    }
}

extern "C" void kernel_launch(void* const* d_in, const int* in_sizes, int n_in,
                              void* d_out, int out_size, void* d_ws, size_t ws_size,
                              hipStream_t stream)
{
    const float* inputs = (const float*)d_in[0];
    const float* w_ih   = (const float*)d_in[1];
    const float* w_hh   = (const float*)d_in[2];
    const float* b_ih   = (const float*)d_in[3];
    const float* b_hh   = (const float*)d_in[4];
    const float* c1w    = (const float*)d_in[5];
    const float* c1b    = (const float*)d_in[6];
    const float* c2w    = (const float*)d_in[7];
    const float* c2b    = (const float*)d_in[8];
    const float* c3w    = (const float*)d_in[9];
    const float* c3b    = (const float*)d_in[10];
    const float* c4w    = (const float*)d_in[11];
    const float* c4b    = (const float*)d_in[12];
    const float* fc1w   = (const float*)d_in[13];
    const float* fc1b   = (const float*)d_in[14];
    const float* fc2w   = (const float*)d_in[15];
    const float* fc2b   = (const float*)d_in[16];
    const float* fc3w   = (const float*)d_in[17];
    const float* fc3b   = (const float*)d_in[18];
    float* out = (float*)d_out;
    const int T = in_sizes[0] / ESZ;   // 4096

    // ---- workspace layout (floats) ----
    float* p = (float*)d_ws;
    unsigned long long* hpack = (unsigned long long*)p;  // 2*512 u64 = 2048 f
    float* hmean = p + 2048;                  // 512
    float* X1 = p + 2560;                     // 512*2100 = 1075200
    float* C1 = X1 + 1075200;                 // 512*256  = 131072
    float* s1 = C1 + 131072;                  // 256*256  = 65536
    float* X2 = s1 + 65536;                   // 256*1280 = 327680
    float* C2 = X2 + 327680;                  // 256*64   = 16384
    float* s2 = C2 + 16384;                   // 64*128   = 8192
    float* X3 = s2 + 8192;                    // 128*192  = 24576
    float* C3 = X3 + 24576;                   // 128*256  = 32768
    float* s3 = C3 + 32768;                   // 256*64   = 16384
    float* X4 = s3 + 16384;                   // 64*256   = 16384
    float* C4 = X4 + 16384;                   // 64*16    = 1024
    float* yb = C4 + 1024;                    // 1024
    float* x2 = yb + 1024;                    // 128
    float* G  = x2 + 128;                     // T*2048 floats (32 MB @ T=4096)
    const size_t need_bytes = ((size_t)(x2 + 128 - p) + (size_t)T * 2048) * 4;
    const bool use_g = ws_size >= need_bytes;

    // zero hpack (h_0 = 0, tag 0) — re-run/replay safe
    hipMemsetAsync(p, 0, 2048 * sizeof(float), stream);

    if (use_g) {
        // G = inputs * w_ih^T + b_ih + b_hh   [T x 2048]
        gemm_g<<<dim3(2048 / 64, (T + 63) / 64), 256, 0, stream>>>(
            inputs, w_ih, b_ih, b_hh, G, T, 2048, ESZ);
        lstm_kernel<true><<<NBLK, 256, 0, stream>>>(
            inputs, w_ih, w_hh, b_ih, b_hh, G, hpack, hmean, T);
    } else {
        lstm_kernel<false><<<NBLK, 256, 0, stream>>>(
            inputs, w_ih, w_hh, b_ih, b_hh, (const float*)nullptr,
            hpack, hmean, T);
    }

    // ---- CNN branch ----
    im2col1<<<4200, 256, 0, stream>>>(inputs, X1);
    gemm32<<<dim3(8, 16), 256, 0, stream>>>(X1, c1w, c1b, C1, 512, 256, 2100);
    poolsig<<<256, 256, 0, stream>>>(C1, s1, 256, 256);

    im2colN<<<1280, 256, 0, stream>>>(s1, X2, 256, 256, 5, 2, 256 * 1280);
    gemm32<<<dim3(2, 8), 256, 0, stream>>>(X2, c2w, c2b, C2, 256, 64, 1280);
    poolsig<<<32, 256, 0, stream>>>(C2, s2, 64, 128);

    im2colN<<<96, 256, 0, stream>>>(s2, X3, 128, 64, 3, 1, 128 * 192);
    gemm32<<<dim3(8, 4), 256, 0, stream>>>(X3, c3w, c3b, C3, 128, 256, 192);
    poolsig<<<64, 256, 0, stream>>>(C3, s3, 256, 64);

    transpose4<<<64, 256, 0, stream>>>(s3, X4);
    gemm32<<<dim3(1, 2), 256, 0, stream>>>(X4, c4w, c4b, C4, 64, 16, 256);
    sigy<<<4, 256, 0, stream>>>(C4, yb);

    // ---- MLP head ----
    fc1_kernel<<<128, 64, 0, stream>>>(hmean, yb, fc1w, fc1b, x2);
    head_kernel<<<1, 64, 0, stream>>>(x2, fc2w, fc2b, fc3w, fc3b, out);
}